// Round 6
// baseline (878.764 us; speedup 1.0000x reference)
//
#include <hip/hip_runtime.h>
#include <math.h>

#define B_  8
#define S_  16
#define H_  32
#define W_  32
#define E_  128
#define NH_ 8
#define HD_ 16
#define HW_ (H_*W_)            // 1024
#define NTOK (B_*S_*H_*W_)     // 131072

typedef __attribute__((ext_vector_type(8))) short short8;
typedef __attribute__((ext_vector_type(4))) short short4v;
typedef __attribute__((ext_vector_type(4))) float floatx4;

__device__ __forceinline__ float sigf(float x){
    return 1.f/(1.f+__expf(-x));
}
__device__ __forceinline__ float tanh_fast(float x){
    x = fminf(fmaxf(x, -15.f), 15.f);
    float e = __expf(2.f*x);
    return (e-1.f)/(e+1.f);
}
__device__ __forceinline__ unsigned short f2bf(float f){
    unsigned int u = __float_as_uint(f);
    u = (u + 0x7fffu + ((u >> 16) & 1u)) >> 16;   // RNE
    return (unsigned short)u;
}
__device__ __forceinline__ float bf2f(unsigned short h){
    return __uint_as_float(((unsigned int)h) << 16);
}

__device__ __forceinline__ void st_gate(float* p, float v){ *p = v; }
__device__ __forceinline__ void st_gate(unsigned short* p, float v){ *p = f2bf(v); }
__device__ __forceinline__ void load_gate(const float* p, float* o){
    float4 v = *(const float4*)p; o[0]=v.x; o[1]=v.y; o[2]=v.z; o[3]=v.w;
}
__device__ __forceinline__ void load_gate(const unsigned short* p, float* o){
    ushort4 v = *(const ushort4*)p;
    o[0]=bf2f(v.x); o[1]=bf2f(v.y); o[2]=bf2f(v.z); o[3]=bf2f(v.w);
}

// ---------------------------------------------------------------------------
// W_proj (128x128 fp32) -> split-bf16 B' fragments for K=384 GEMM:
//   B' rows  0..127 = bf16_hi(W)   (pairs with Ah)
//   B' rows 128..255 = bf16_hi(W)  (pairs with Al)
//   B' rows 256..383 = bf16_lo(W)  (pairs with Ah)
// packet (nt*12+kb)*64+L holds B'[k=kb*32+(L>>4)*8+j][n=nt*16+(L&15)], j=0..7
__global__ __launch_bounds__(256)
void k_pack_wproj(const float* __restrict__ Wp, short* __restrict__ Wpp){
    int p = blockIdx.x*256 + threadIdx.x;    // 6144 packets
    int L = p & 63;
    int idx = p >> 6;                        // nt*12 + kb
    int nt = idx / 12, kb = idx - nt*12;
    int n = nt*16 + (L & 15);
    int kr = (kb & 3)*32 + (L >> 4)*8;
    bool lo = (kb >= 8);
    short8 v;
    #pragma unroll
    for (int j=0;j<8;j++){
        float wv = Wp[(kr+j)*128 + n];
        unsigned short h = f2bf(wv);
        v[j] = lo ? (short)f2bf(wv - bf2f(h)) : (short)h;
    }
    *(short8*)&Wpp[(long)p*8] = v;
}

// ---------------------------------------------------------------------------
// X = LayerNorm(silu(inputs @ W_proj)) via split-bf16 MFMA (fp32-accurate).
// Block = 64 token rows, 4 waves (wave w owns rows w*16..w*16+15).
// A' staged in LDS: row = [Ah(128) | Al(128) | pad(8)] shorts, stride 264
// (528 B -> consecutive rows shift 4 banks; ds_read_b128 is 2-way max = free).
__global__ __launch_bounds__(256,2)
void k_proj_ln_mfma(const float* __restrict__ in, const short* __restrict__ Wpp,
                    const float* __restrict__ gamma, const float* __restrict__ beta,
                    float* __restrict__ X){
    __shared__ short As[64*264];             // 33,792 B
    int tid = threadIdx.x;
    int w = tid >> 6, L = tid & 63;
    int quad = L >> 4, lm = L & 15;
    long r0 = (long)blockIdx.x * 64;

    // stage: 64 rows x 128 f32 -> split bf16 (coalesced float4 loads)
    {
        int c = (tid & 31)*4;
        int rbase = tid >> 5;
        #pragma unroll
        for (int rr=0; rr<8; rr++){
            int r = rr*8 + rbase;
            float4 v = *(const float4*)&in[(r0 + r)*128 + c];
            short4v hv, lv;
            unsigned short h;
            h = f2bf(v.x); hv[0]=(short)h; lv[0]=(short)f2bf(v.x - bf2f(h));
            h = f2bf(v.y); hv[1]=(short)h; lv[1]=(short)f2bf(v.y - bf2f(h));
            h = f2bf(v.z); hv[2]=(short)h; lv[2]=(short)f2bf(v.z - bf2f(h));
            h = f2bf(v.w); hv[3]=(short)h; lv[3]=(short)f2bf(v.w - bf2f(h));
            *(short4v*)&As[r*264 + c] = hv;
            *(short4v*)&As[r*264 + 128 + c] = lv;
        }
    }
    __syncthreads();

    floatx4 acc[8];
    #pragma unroll
    for (int nt=0;nt<8;nt++) acc[nt] = (floatx4){0.f,0.f,0.f,0.f};
    const short8* Bp8 = (const short8*)Wpp;
    int arow = (w*16 + lm)*264 + quad*8;
    #pragma unroll
    for (int kb=0; kb<12; kb++){
        int off = (kb<4) ? kb*32 : ((kb<8) ? 128+(kb-4)*32 : (kb-8)*32);
        short8 af = *(const short8*)&As[arow + off];
        #pragma unroll
        for (int nt=0;nt<8;nt++){
            short8 bf = Bp8[(nt*12+kb)*64 + L];
            acc[nt] = __builtin_amdgcn_mfma_f32_16x16x32_bf16(af, bf, acc[nt], 0,0,0);
        }
    }

    // fused silu + LayerNorm epilogue.
    // C layout: row = quad*4+r (within wave's 16), col = nt*16+lm.
    // LN reduce over N = 8 regs + shfl_xor over the 16-lane (lm) group.
    float g[8], bb[8];
    #pragma unroll
    for (int nt=0;nt<8;nt++){ g[nt]=gamma[nt*16+lm]; bb[nt]=beta[nt*16+lm]; }
    float s1[4]={0,0,0,0}, s2[4]={0,0,0,0};
    #pragma unroll
    for (int nt=0;nt<8;nt++)
        #pragma unroll
        for (int r=0;r<4;r++){
            float a = acc[nt][r];
            float si = a*sigf(a);                 // silu
            acc[nt][r] = si;
            s1[r] += si; s2[r] += si*si;
        }
    #pragma unroll
    for (int d=1; d<16; d<<=1)
        #pragma unroll
        for (int r=0;r<4;r++){
            s1[r] += __shfl_xor(s1[r], d);
            s2[r] += __shfl_xor(s2[r], d);
        }
    float mu[4], rs[4];
    #pragma unroll
    for (int r=0;r<4;r++){
        mu[r] = s1[r]*(1.f/128.f);
        float var = s2[r]*(1.f/128.f) - mu[r]*mu[r];
        rs[r] = rsqrtf(var + 1e-5f);
    }
    #pragma unroll
    for (int nt=0;nt<8;nt++)
        #pragma unroll
        for (int r=0;r<4;r++){
            long row = r0 + w*16 + quad*4 + r;
            X[row*128 + nt*16 + lm] = (acc[nt][r]-mu[r])*rs[r]*g[nt] + bb[nt];
        }
}

// ---------------------------------------------------------------------------
// W_in (128x384) -> bf16 B-fragment packets: packet (nt*4+kc)*64+L holds
// B[k=kc*32+(L>>4)*8+j][n=nt*16+(L&15)], j=0..7
__global__ __launch_bounds__(256)
void k_pack_win(const float* __restrict__ Win, short* __restrict__ Winp){
    int p = blockIdx.x*256 + threadIdx.x;    // 6144 packets
    int L = p & 63;
    int idx = p >> 6;                        // nt*4+kc
    int nt = idx >> 2, kc = idx & 3;
    int n = nt*16 + (L & 15);
    int k0 = kc*32 + (L >> 4)*8;
    short8 v;
    #pragma unroll
    for (int j=0;j<8;j++) v[j] = (short)f2bf(Win[(k0+j)*384 + n]);
    *(short8*)&Winp[(long)p*8] = v;
}

// ---------------------------------------------------------------------------
// W_out (128x128) -> per-head zero-padded B packets: packet (h*8+nt)*64+L:
// B[k=(L>>4)*8+j][n=nt*16+(L&15)] = (k<16) ? Wout[h*16+k][n] : 0
__global__ __launch_bounds__(256)
void k_pack_wout(const float* __restrict__ Wout, short* __restrict__ Woutp){
    int p = blockIdx.x*256 + threadIdx.x;    // 4096 packets
    int L = p & 63;
    int idx = p >> 6;                        // h*8+nt
    int h = idx >> 3, nt = idx & 7;
    int n = nt*16 + (L & 15);
    int k0 = (L >> 4)*8;
    short8 v;
    #pragma unroll
    for (int j=0;j<8;j++){
        int k = k0 + j;
        v[j] = (k < 16) ? (short)f2bf(Wout[(h*16+k)*128 + n]) : (short)0;
    }
    *(short8*)&Woutp[(long)p*8] = v;
}

// ---------------------------------------------------------------------------
// Fused MFMA attention. Block = (b, 4 hw-sites), M=64 rows (site*16+s).
// 4 waves, each owns ONE site; ALL LDS traffic is wave-local (no barriers).
__global__ __launch_bounds__(256,5)
void k_attn_mfma(const float* __restrict__ X, const short* __restrict__ Winp,
                 const short* __restrict__ Woutp, const float* __restrict__ resid,
                 float* __restrict__ Y){
    __shared__ short lds[16000];             // 32,000 B
    const int XO=0;                          // X tile  [64][136]
    const int QO=8704;                       // Q plain [64][24]
    const int KO=10240;                      // K plain [64][24]
    const int VO=11776;                      // V^T     [16][72] (cols = m)
    const int PO=12928;                      // P plain [64][24]
    const int AOO=14464;                     // ao      [64][24]
    int tid = threadIdx.x;
    int w = tid >> 6, L = tid & 63;
    int quad = L >> 4, lm = L & 15;
    int b = blockIdx.x >> 8, tile = blockIdx.x & 255;
    int hw0 = tile * 4;
    int hw = hw0 + w;                        // this wave's site

    // phase 1: wave-local X rows w*16..w*16+15 (site w), fp32->bf16
    {
        int cq = L & 31, rh = L >> 5;
        for (int p=0; p<8; p++){
            int m = w*16 + p*2 + rh;
            int s = m & 15;
            float4 v = *(const float4*)&X[((((long)b*16 + s)*1024) + hw)*128 + cq*4];
            short4v hv;
            hv[0]=(short)f2bf(v.x); hv[1]=(short)f2bf(v.y);
            hv[2]=(short)f2bf(v.z); hv[3]=(short)f2bf(v.w);
            *(short4v*)&lds[XO + m*136 + cq*4] = hv;
        }
    }

    floatx4 Oa[8];
    #pragma unroll
    for (int nt=0;nt<8;nt++) Oa[nt] = (floatx4){0.f,0.f,0.f,0.f};

    const floatx4 zc = (floatx4){0.f,0.f,0.f,0.f};
    const short8 z8 = {0,0,0,0,0,0,0,0};
    int m0 = w*16;

    for (int h=0; h<8; h++){
        // ---- phase 2: QKV GEMM for n-tiles {3h, 3h+1, 3h+2} = q,k,v of head h
        floatx4 qacc[3];
        #pragma unroll
        for (int t=0;t<3;t++) qacc[t] = zc;
        #pragma unroll
        for (int kc=0;kc<4;kc++){
            short8 af = *(const short8*)&lds[XO + (m0+lm)*136 + kc*32 + quad*8];
            #pragma unroll
            for (int t=0;t<3;t++){
                int nt = 3*h + t;
                short8 bf = *(const short8*)&Winp[(long)((nt*4+kc)*64 + L)*8];
                qacc[t] = __builtin_amdgcn_mfma_f32_16x16x32_bf16(af, bf, qacc[t], 0,0,0);
            }
        }
        // epilogue: Q,K -> plain [m][d]; V -> V^T [d][m]
        #pragma unroll
        for (int r=0;r<4;r++){
            lds[QO + (m0+quad*4+r)*24 + lm] = (short)f2bf(qacc[0][r]);
            lds[KO + (m0+quad*4+r)*24 + lm] = (short)f2bf(qacc[1][r]);
        }
        {
            short4v vv;
            #pragma unroll
            for (int r=0;r<4;r++) vv[r] = (short)f2bf(qacc[2][r]);
            *(short4v*)&lds[VO + lm*72 + m0 + quad*4] = vv;
        }

        // ---- phase 3: per-site scores -> softmax -> PV ----
        {
            short8 qf = z8, kf = z8;
            if (quad < 2){
                qf = *(const short8*)&lds[QO + (m0+lm)*24 + quad*8];
                kf = *(const short8*)&lds[KO + (m0+lm)*24 + quad*8];
            }
            floatx4 scv = __builtin_amdgcn_mfma_f32_16x16x32_bf16(qf, kf, zc, 0,0,0);
            float pv[4], mr[4];
            #pragma unroll
            for (int r=0;r<4;r++){
                int si = quad*4 + r;
                pv[r] = scv[r]*0.25f + (lm <= si ? 1.0f : -1000.0f);
                mr[r] = pv[r];
            }
            #pragma unroll
            for (int d=1; d<16; d<<=1)
                #pragma unroll
                for (int r=0;r<4;r++) mr[r] = fmaxf(mr[r], __shfl_xor(mr[r], d));
            float ex[4], sm[4];
            #pragma unroll
            for (int r=0;r<4;r++){ ex[r] = __expf(pv[r]-mr[r]); sm[r] = ex[r]; }
            #pragma unroll
            for (int d=1; d<16; d<<=1)
                #pragma unroll
                for (int r=0;r<4;r++) sm[r] += __shfl_xor(sm[r], d);
            #pragma unroll
            for (int r=0;r<4;r++)
                lds[PO + (m0+quad*4+r)*24 + lm] = (short)f2bf(ex[r]/sm[r]);

            short8 pf = z8, vf = z8;
            if (quad < 2){
                pf = *(const short8*)&lds[PO + (m0+lm)*24 + quad*8];
                vf = *(const short8*)&lds[VO + lm*72 + m0 + quad*8];
            }
            floatx4 aov = __builtin_amdgcn_mfma_f32_16x16x32_bf16(pf, vf, zc, 0,0,0);
            #pragma unroll
            for (int r=0;r<4;r++)
                lds[AOO + (m0+quad*4+r)*24 + lm] = (short)f2bf(aov[r]);
        }

        // ---- phase 4: O += ao_h @ Wout[h-rows] ----
        {
            short8 aof = z8;
            if (quad < 2)
                aof = *(const short8*)&lds[AOO + (m0+lm)*24 + quad*8];
            #pragma unroll
            for (int nt=0;nt<8;nt++){
                short8 wf = *(const short8*)&Woutp[(long)((h*8+nt)*64 + L)*8];
                Oa[nt] = __builtin_amdgcn_mfma_f32_16x16x32_bf16(aof, wf, Oa[nt], 0,0,0);
            }
        }
    }

    // epilogue: O + residual -> Y (in place over X rows this block loaded)
    #pragma unroll
    for (int nt=0;nt<8;nt++){
        int n = nt*16 + lm;
        #pragma unroll
        for (int r=0;r<4;r++){
            int s = quad*4 + r;
            long addr = (((long)b*16 + s)*1024 + hw)*128 + n;
            Y[addr] = Oa[nt][r] + resid[addr];
        }
    }
}

// ---------------------------------------------------------------------------
// Weights -> B-fragment packets, bf16 (conv GEMM).
__global__ __launch_bounds__(256)
void k_pack_w(const float* __restrict__ ck, short* __restrict__ Bp){
    int p = blockIdx.x*256 + threadIdx.x;     // 147456 exact
    int L = p & 63;
    int nt = (p >> 6) & 31;
    int c32 = (p >> 11) & 7;
    int tap = p >> 14;
    int oc = nt*16 + (L & 15);
    int kq = L >> 4;
    short8 v;
    #pragma unroll
    for (int j=0;j<8;j++){
        int ic = c32*32 + kq*8 + j;
        v[j] = (short)f2bf(ck[(oc*256+ic)*9 + tap]);
    }
    *(short8*)&Bp[(long)p*8] = v;
}

// ---------------------------------------------------------------------------
// Pack X slice s (fp32) -> bf16 x-half of xh[row][0:128]; zero h-half at s==0
// (only used once for s=0; the lstm kernel packs slices 1..15 inline)
__global__ __launch_bounds__(256)
void k_pack_x(const float* __restrict__ X, short* __restrict__ xh, int s, int zero_h){
    int idx = blockIdx.x*256 + threadIdx.x;   // 131072
    int row = idx >> 4;
    int ch = (idx & 15) * 8;
    int b = row >> 10, hw = row & 1023;
    const float* src = X + (((long)(b*16+s)*1024 + hw)*128 + ch);
    float4 a = *(const float4*)src;
    float4 c = *(const float4*)(src+4);
    short8 v;
    v[0]=(short)f2bf(a.x); v[1]=(short)f2bf(a.y); v[2]=(short)f2bf(a.z); v[3]=(short)f2bf(a.w);
    v[4]=(short)f2bf(c.x); v[5]=(short)f2bf(c.y); v[6]=(short)f2bf(c.z); v[7]=(short)f2bf(c.w);
    *(short8*)&xh[(long)row*256 + ch] = v;
    if (zero_h){
        short8 z = {0,0,0,0,0,0,0,0};
        *(short8*)&xh[(long)row*256 + 128 + ch] = z;
    }
}

// ---------------------------------------------------------------------------
// Implicit-im2col MFMA GEMM: gates[8192][512] = patches(xh) @ W.
// R6 rework: R4/R5 ran 1 block/CU -> staging barrier + epilogue drain had
// nothing to overlap with (both restructures stalled at ~36-40 us). Now
// Ntile 128 (grid 512 = 2 blocks/CU co-resident: LDS 2x71,808 = 143.6 KB
// < 160 KB), 8 waves = 2 wm x 4 wn, wave = 2 m-tiles x 2 n-tiles. One
// block's K-loop hides the other's staging/epilogue. Accumulation order
// (tap,sic,c2) and operands unchanged -> bit-identical gbuf.
template<typename GT>
__global__ __launch_bounds__(512,4)
void k_conv_mfma(const short* __restrict__ xh, const short* __restrict__ Bp,
                 GT* __restrict__ gbuf){
    __shared__ short As[4*34*264];           // 71,808 B
    int tid = threadIdx.x;
    int Nblk = blockIdx.x & 3, g = blockIdx.x >> 2;      // g 0..127
    int b = g >> 4, y0 = (g & 15)*2;
    int w = tid >> 6, L = tid & 63;
    int quad = L >> 4, lm = L & 15;
    int wm = w >> 2, wn = w & 3;             // wave -> (m-pair, n-pair)
    int ntg = Nblk*8 + wn*2;                 // first of this wave's 2 n-tiles

    // ---- stage A halo: rows y0-1..y0+2, x -1..32, ch 0..255 (zero-padded)
    // 4352 packets in 9 rounds of 512; loads batched to regs, then stores.
    const short8 z8 = {0,0,0,0,0,0,0,0};
    {
        short8 vs[9];
        #pragma unroll
        for (int i=0; i<9; i++){
            int pidx = i*512 + tid;
            short8 v = z8;
            if (pidx < 4352){
                int cb  = pidx & 31;             // 8-ch granule
                int pos = pidx >> 5;             // row*34 + xp
                int row = pos / 34;
                int xp  = pos - row*34;
                int yy = y0 - 1 + row, xx = xp - 1;
                if (yy>=0 && yy<32 && xx>=0 && xx<32)
                    v = *(const short8*)&xh[(((long)(b*32+yy)*32+xx)<<8) + cb*8];
            }
            vs[i] = v;
        }
        #pragma unroll
        for (int i=0; i<9; i++){
            int pidx = i*512 + tid;
            if (pidx < 4352){
                int cb  = pidx & 31;
                int pos = pidx >> 5;
                *(short8*)&As[pos*264 + cb*8] = vs[i];
            }
        }
    }
    __syncthreads();

    floatx4 acc[2][2];
    #pragma unroll
    for (int mtl=0;mtl<2;mtl++)
        #pragma unroll
        for (int nti=0;nti<2;nti++)
            acc[mtl][nti] = (floatx4){0.f,0.f,0.f,0.f};

    const short8* Bp8 = (const short8*)Bp;

    for (int tap=0; tap<9; tap++){
        int dy = tap/3 - 1, dx = tap - (tap/3)*3 - 1;
        // per-mtl A line base (shorts): mt = wm*2+mtl -> ys=wm, x=mtl*16+lm
        int abase[2];
        #pragma unroll
        for (int mtl=0;mtl<2;mtl++){
            int x = mtl*16 + lm;
            abase[mtl] = (((wm+dy+1)*34) + x + dx + 1)*264 + quad*8;
        }
        #pragma unroll
        for (int sic=0; sic<4; sic++){
            #pragma unroll
            for (int c2=0; c2<2; c2++){
                short8 bfr[2];
                #pragma unroll
                for (int nti=0;nti<2;nti++)
                    bfr[nti] = Bp8[((tap*8 + sic*2 + c2)*32 + ntg + nti)*64 + L];
                #pragma unroll
                for (int mtl=0;mtl<2;mtl++){
                    short8 afr = *(const short8*)&As[abase[mtl] + sic*64 + c2*32];
                    #pragma unroll
                    for (int nti=0;nti<2;nti++)
                        acc[mtl][nti] = __builtin_amdgcn_mfma_f32_16x16x32_bf16(afr, bfr[nti], acc[mtl][nti], 0,0,0);
                }
            }
        }
    }

    #pragma unroll
    for (int mtl=0;mtl<2;mtl++){
        #pragma unroll
        for (int nti=0;nti<2;nti++){
            int n = Nblk*128 + (wn*2+nti)*16 + lm;
            #pragma unroll
            for (int r=0;r<4;r++){
                long row = (long)g*64 + (wm*2+mtl)*16 + quad*4 + r;
                st_gate(&gbuf[row*512 + n], acc[mtl][nti][r]);
            }
        }
    }
}

// ---------------------------------------------------------------------------
// Fused LSTM pointwise + inline pack of next slice's x-half (replaces k_pack_x
// for s=1..15: X is fixed after attention, and lstm already touches every
// (row, c4), so packing here saves a dependent launch per step)
template<typename GT>
__global__ __launch_bounds__(256)
void k_lstm(const GT* __restrict__ gbuf, float* __restrict__ cbuf,
            float* __restrict__ X, short* __restrict__ xh, int s){
    int idx = blockIdx.x*256 + threadIdx.x;    // 262144
    int row = idx >> 5;
    int c4 = (idx & 31)*4;
    float gi[4], gf[4], go[4], gg[4];
    const GT* gp = gbuf + (long)row*512 + c4;
    load_gate(gp,       gi);
    load_gate(gp + 128, gf);
    load_gate(gp + 256, go);
    load_gate(gp + 384, gg);
    float co[4];
    if (s == 0){ co[0]=co[1]=co[2]=co[3]=0.f; }
    else {
        float4 cv = *(const float4*)&cbuf[(long)row*128 + c4];
        co[0]=cv.x; co[1]=cv.y; co[2]=cv.z; co[3]=cv.w;
    }
    float cn[4], hn[4];
    #pragma unroll
    for (int j=0;j<4;j++){
        cn[j] = sigf(gf[j])*co[j] + sigf(gi[j])*tanh_fast(gg[j]);
        hn[j] = sigf(go[j])*tanh_fast(cn[j]);
    }
    *(float4*)&cbuf[(long)row*128 + c4] = make_float4(cn[0],cn[1],cn[2],cn[3]);
    int b = row >> 10, hw = row & 1023;
    long xoff = (((long)(b*16+s)*1024 + hw)*128) + c4;
    *(float4*)&X[xoff] = make_float4(hn[0],hn[1],hn[2],hn[3]);
    ushort4 hv;
    hv.x = f2bf(hn[0]); hv.y = f2bf(hn[1]); hv.z = f2bf(hn[2]); hv.w = f2bf(hn[3]);
    *(ushort4*)&xh[(long)row*256 + 128 + c4] = hv;
    // pack next slice's x-half (attn output slice s+1 is untouched: lstm steps
    // only overwrite their own slice, ascending)
    if (s < 15){
        long x2 = (((long)(b*16+s+1)*1024 + hw)*128) + c4;
        float4 xv = *(const float4*)&X[x2];
        ushort4 xb;
        xb.x = f2bf(xv.x); xb.y = f2bf(xv.y); xb.z = f2bf(xv.z); xb.w = f2bf(xv.w);
        *(ushort4*)&xh[(long)row*256 + c4] = xb;
    }
}

// ---------------------------------------------------------------------------
extern "C" void kernel_launch(void* const* d_in, const int* in_sizes, int n_in,
                              void* d_out, int out_size, void* d_ws, size_t ws_size,
                              hipStream_t stream){
    const float* inputs = (const float*)d_in[0];
    const float* Wp     = (const float*)d_in[1];
    const float* gamma  = (const float*)d_in[2];
    const float* beta   = (const float*)d_in[3];
    const float* Win    = (const float*)d_in[4];
    const float* Wout   = (const float*)d_in[5];
    const float* ck     = (const float*)d_in[6];
    float* X = (float*)d_out;

    char* ws = (char*)d_ws;
    const size_t szB    = 147456ull*16;        // 2,359,296
    const size_t szXH   = 8192ull*256*2;       // 4,194,304
    const size_t szC    = 8192ull*128*4;       // 4,194,304
    const size_t szWin  = 6144ull*16;          //    98,304
    const size_t szWout = 4096ull*16;          //    65,536
    short* Bp    = (short*)(ws);
    short* xh    = (short*)(ws + szB);
    float* cbuf  = (float*)(ws + szB + szXH);
    short* Winp  = (short*)(ws + szB + szXH + szC);
    short* Woutp = (short*)(ws + szB + szXH + szC + szWin);
    char*  gch   =         ws + szB + szXH + szC + szWin + szWout;
    bool gate_f32 = ws_size >= (szB + szXH + szC + szWin + szWout + 8192ull*512*4);
    // W_proj split-bf16 packets (98,304 B) alias the gbuf region: consumed by
    // k_proj_ln_mfma before the scan loop's first k_conv_mfma write to gbuf.
    short* Wprojp = (short*)gch;

    k_pack_w<<<576, 256, 0, stream>>>(ck, Bp);
    k_pack_win<<<24, 256, 0, stream>>>(Win, Winp);
    k_pack_wout<<<16, 256, 0, stream>>>(Wout, Woutp);
    k_pack_wproj<<<24, 256, 0, stream>>>(Wp, Wprojp);
    k_proj_ln_mfma<<<NTOK/64, 256, 0, stream>>>(inputs, Wprojp, gamma, beta, X);
    k_attn_mfma<<<2048, 256, 0, stream>>>(X, Winp, Woutp, inputs, X);  // in-place
    k_pack_x<<<512, 256, 0, stream>>>(X, xh, 0, 1);

    if (gate_f32){
        float* gbuf = (float*)gch;
        for (int s=0; s<16; s++){
            k_conv_mfma<float><<<512, 512, 0, stream>>>(xh, Bp, gbuf);
            k_lstm<float><<<1024, 256, 0, stream>>>(gbuf, cbuf, X, xh, s);
        }
    } else {
        unsigned short* gbuf = (unsigned short*)gch;
        for (int s=0; s<16; s++){
            k_conv_mfma<unsigned short><<<512, 512, 0, stream>>>(xh, Bp, gbuf);
            k_lstm<unsigned short><<<1024, 256, 0, stream>>>(gbuf, cbuf, X, xh, s);
        }
    }
}

// Round 7
// 863.580 us; speedup vs baseline: 1.0176x; 1.0176x over previous
//
#include <hip/hip_runtime.h>
#include <math.h>

#define B_  8
#define S_  16
#define H_  32
#define W_  32
#define E_  128
#define NH_ 8
#define HD_ 16
#define HW_ (H_*W_)            // 1024
#define NTOK (B_*S_*H_*W_)     // 131072

typedef __attribute__((ext_vector_type(8))) short short8;
typedef __attribute__((ext_vector_type(4))) short short4v;
typedef __attribute__((ext_vector_type(4))) float floatx4;

__device__ __forceinline__ float sigf(float x){
    return 1.f/(1.f+__expf(-x));
}
__device__ __forceinline__ float tanh_fast(float x){
    x = fminf(fmaxf(x, -15.f), 15.f);
    float e = __expf(2.f*x);
    return (e-1.f)/(e+1.f);
}
__device__ __forceinline__ unsigned short f2bf(float f){
    unsigned int u = __float_as_uint(f);
    u = (u + 0x7fffu + ((u >> 16) & 1u)) >> 16;   // RNE
    return (unsigned short)u;
}
__device__ __forceinline__ float bf2f(unsigned short h){
    return __uint_as_float(((unsigned int)h) << 16);
}

__device__ __forceinline__ void st_gate(float* p, float v){ *p = v; }
__device__ __forceinline__ void st_gate(unsigned short* p, float v){ *p = f2bf(v); }
__device__ __forceinline__ void load_gate(const float* p, float* o){
    float4 v = *(const float4*)p; o[0]=v.x; o[1]=v.y; o[2]=v.z; o[3]=v.w;
}
__device__ __forceinline__ void load_gate(const unsigned short* p, float* o){
    ushort4 v = *(const ushort4*)p;
    o[0]=bf2f(v.x); o[1]=bf2f(v.y); o[2]=bf2f(v.z); o[3]=bf2f(v.w);
}

// ---------------------------------------------------------------------------
// W_proj (128x128 fp32) -> split-bf16 B' fragments for K=384 GEMM:
//   B' rows  0..127 = bf16_hi(W)   (pairs with Ah)
//   B' rows 128..255 = bf16_hi(W)  (pairs with Al)
//   B' rows 256..383 = bf16_lo(W)  (pairs with Ah)
// packet (nt*12+kb)*64+L holds B'[k=kb*32+(L>>4)*8+j][n=nt*16+(L&15)], j=0..7
__global__ __launch_bounds__(256)
void k_pack_wproj(const float* __restrict__ Wp, short* __restrict__ Wpp){
    int p = blockIdx.x*256 + threadIdx.x;    // 6144 packets
    int L = p & 63;
    int idx = p >> 6;                        // nt*12 + kb
    int nt = idx / 12, kb = idx - nt*12;
    int n = nt*16 + (L & 15);
    int kr = (kb & 3)*32 + (L >> 4)*8;
    bool lo = (kb >= 8);
    short8 v;
    #pragma unroll
    for (int j=0;j<8;j++){
        float wv = Wp[(kr+j)*128 + n];
        unsigned short h = f2bf(wv);
        v[j] = lo ? (short)f2bf(wv - bf2f(h)) : (short)h;
    }
    *(short8*)&Wpp[(long)p*8] = v;
}

// ---------------------------------------------------------------------------
// X = LayerNorm(silu(inputs @ W_proj)) via split-bf16 MFMA (fp32-accurate).
// R7 rework: old wave = 1 m-tile x 8 n-tiles -> each wave streamed the whole
// 96 KB Wpp per 16 rows = 786 MB L2 traffic/dispatch (~23 us serial) with
// MfmaUtil 6.7%. Now wave = 4 m-tiles x 2 n-tiles: B per wave 24 KB (chip
// 196 MB), A ds_read feeds 2 MFMAs. LN row-sum now spans 4 waves -> partial
// sums to LDS red[] + barrier. Per-accumulator kb order unchanged.
__global__ __launch_bounds__(256,4)
void k_proj_ln_mfma(const float* __restrict__ in, const short* __restrict__ Wpp,
                    const float* __restrict__ gamma, const float* __restrict__ beta,
                    float* __restrict__ X){
    __shared__ short As[64*264];             // 33,792 B
    __shared__ float red[4][64][2];          //  2,048 B
    int tid = threadIdx.x;
    int w = tid >> 6, L = tid & 63;
    int quad = L >> 4, lm = L & 15;
    long r0 = (long)blockIdx.x * 64;

    // stage: 64 rows x 128 f32 -> split bf16 (coalesced float4 loads)
    {
        int c = (tid & 31)*4;
        int rbase = tid >> 5;
        #pragma unroll
        for (int rr=0; rr<8; rr++){
            int r = rr*8 + rbase;
            float4 v = *(const float4*)&in[(r0 + r)*128 + c];
            short4v hv, lv;
            unsigned short h;
            h = f2bf(v.x); hv[0]=(short)h; lv[0]=(short)f2bf(v.x - bf2f(h));
            h = f2bf(v.y); hv[1]=(short)h; lv[1]=(short)f2bf(v.y - bf2f(h));
            h = f2bf(v.z); hv[2]=(short)h; lv[2]=(short)f2bf(v.z - bf2f(h));
            h = f2bf(v.w); hv[3]=(short)h; lv[3]=(short)f2bf(v.w - bf2f(h));
            *(short4v*)&As[r*264 + c] = hv;
            *(short4v*)&As[r*264 + 128 + c] = lv;
        }
    }
    __syncthreads();

    floatx4 acc[4][2];
    #pragma unroll
    for (int mtl=0;mtl<4;mtl++)
        #pragma unroll
        for (int nti=0;nti<2;nti++)
            acc[mtl][nti] = (floatx4){0.f,0.f,0.f,0.f};
    const short8* Bp8 = (const short8*)Wpp;
    #pragma unroll
    for (int kb=0; kb<12; kb++){
        int off = (kb<4) ? kb*32 : ((kb<8) ? 128+(kb-4)*32 : (kb-8)*32);
        short8 af[4];
        #pragma unroll
        for (int mtl=0;mtl<4;mtl++)
            af[mtl] = *(const short8*)&As[(mtl*16+lm)*264 + off + quad*8];
        #pragma unroll
        for (int nti=0;nti<2;nti++){
            short8 bf = Bp8[((2*w+nti)*12+kb)*64 + L];
            #pragma unroll
            for (int mtl=0;mtl<4;mtl++)
                acc[mtl][nti] = __builtin_amdgcn_mfma_f32_16x16x32_bf16(af[mtl], bf, acc[mtl][nti], 0,0,0);
        }
    }

    // fused silu + LayerNorm epilogue (cross-wave row reduction).
    // C layout: row = mtl*16 + quad*4 + r, col = (2w+nti)*16 + lm.
    #pragma unroll
    for (int mtl=0;mtl<4;mtl++){
        float p1[4]={0,0,0,0}, p2[4]={0,0,0,0};
        #pragma unroll
        for (int nti=0;nti<2;nti++)
            #pragma unroll
            for (int r=0;r<4;r++){
                float a = acc[mtl][nti][r];
                float si = a*sigf(a);             // silu
                acc[mtl][nti][r] = si;
                p1[r] += si; p2[r] += si*si;
            }
        #pragma unroll
        for (int d=1; d<16; d<<=1)
            #pragma unroll
            for (int r=0;r<4;r++){
                p1[r] += __shfl_xor(p1[r], d);
                p2[r] += __shfl_xor(p2[r], d);
            }
        if (lm == 0){
            #pragma unroll
            for (int r=0;r<4;r++){
                int row = mtl*16 + quad*4 + r;
                red[w][row][0] = p1[r];
                red[w][row][1] = p2[r];
            }
        }
    }
    __syncthreads();
    float g[2], bb[2];
    #pragma unroll
    for (int nti=0;nti<2;nti++){
        g[nti]  = gamma[(2*w+nti)*16 + lm];
        bb[nti] = beta [(2*w+nti)*16 + lm];
    }
    #pragma unroll
    for (int mtl=0;mtl<4;mtl++){
        #pragma unroll
        for (int r=0;r<4;r++){
            int row = mtl*16 + quad*4 + r;
            float s1 = red[0][row][0] + red[1][row][0] + red[2][row][0] + red[3][row][0];
            float s2 = red[0][row][1] + red[1][row][1] + red[2][row][1] + red[3][row][1];
            float mu  = s1 * (1.f/128.f);
            float var = s2 * (1.f/128.f) - mu*mu;
            float rs  = rsqrtf(var + 1e-5f);
            #pragma unroll
            for (int nti=0;nti<2;nti++)
                X[(r0+row)*128 + (2*w+nti)*16 + lm] = (acc[mtl][nti][r]-mu)*rs*g[nti] + bb[nti];
        }
    }
}

// ---------------------------------------------------------------------------
// W_in (128x384) -> bf16 B-fragment packets: packet (nt*4+kc)*64+L holds
// B[k=kc*32+(L>>4)*8+j][n=nt*16+(L&15)], j=0..7
__global__ __launch_bounds__(256)
void k_pack_win(const float* __restrict__ Win, short* __restrict__ Winp){
    int p = blockIdx.x*256 + threadIdx.x;    // 6144 packets
    int L = p & 63;
    int idx = p >> 6;                        // nt*4+kc
    int nt = idx >> 2, kc = idx & 3;
    int n = nt*16 + (L & 15);
    int k0 = kc*32 + (L >> 4)*8;
    short8 v;
    #pragma unroll
    for (int j=0;j<8;j++) v[j] = (short)f2bf(Win[(k0+j)*384 + n]);
    *(short8*)&Winp[(long)p*8] = v;
}

// ---------------------------------------------------------------------------
// W_out (128x128) -> per-head zero-padded B packets: packet (h*8+nt)*64+L:
// B[k=(L>>4)*8+j][n=nt*16+(L&15)] = (k<16) ? Wout[h*16+k][n] : 0
__global__ __launch_bounds__(256)
void k_pack_wout(const float* __restrict__ Wout, short* __restrict__ Woutp){
    int p = blockIdx.x*256 + threadIdx.x;    // 4096 packets
    int L = p & 63;
    int idx = p >> 6;                        // h*8+nt
    int h = idx >> 3, nt = idx & 7;
    int n = nt*16 + (L & 15);
    int k0 = (L >> 4)*8;
    short8 v;
    #pragma unroll
    for (int j=0;j<8;j++){
        int k = k0 + j;
        v[j] = (k < 16) ? (short)f2bf(Wout[(h*16+k)*128 + n]) : (short)0;
    }
    *(short8*)&Woutp[(long)p*8] = v;
}

// ---------------------------------------------------------------------------
// Fused MFMA attention. R7: block = (b, 8 hw-sites), 4 waves, each wave owns
// TWO sites (halves per-site Winp/Woutp streaming: 1.3 GB -> 655 MB L2) while
// keeping 3 blocks/CU by aliasing P<-Q and AO<-K (each is consumed before its
// alias is written, all wave-local, no barriers). LDS 51,456 B.
__global__ __launch_bounds__(256,2)
void k_attn_mfma(const float* __restrict__ X, const short* __restrict__ Winp,
                 const short* __restrict__ Woutp, const float* __restrict__ resid,
                 float* __restrict__ Y){
    __shared__ short lds[25728];             // 51,456 B
    const int XO=0;                          // X tile  [128][136]
    const int QO=17408;                      // Q plain [128][24]
    const int KO=20480;                      // K plain [128][24]
    const int VO=23552;                      // V^T     [16][136] (cols = m)
    const int PO=QO;                         // P aliases Q (Q consumed first)
    const int AOO=KO;                        // ao aliases K (K consumed first)
    int tid = threadIdx.x;
    int w = tid >> 6, L = tid & 63;
    int quad = L >> 4, lm = L & 15;
    int b = blockIdx.x >> 7, tile = blockIdx.x & 127;
    int hw0 = tile * 8;

    // phase 1: wave-local X rows w*32..w*32+31 (sites 2w, 2w+1), fp32->bf16
    {
        int cq = L & 31, rh = L >> 5;
        for (int p=0; p<16; p++){
            int m = w*32 + p*2 + rh;
            int s = m & 15, st = m >> 4;
            float4 v = *(const float4*)&X[((((long)b*16 + s)*1024) + hw0 + st)*128 + cq*4];
            short4v hv;
            hv[0]=(short)f2bf(v.x); hv[1]=(short)f2bf(v.y);
            hv[2]=(short)f2bf(v.z); hv[3]=(short)f2bf(v.w);
            *(short4v*)&lds[XO + m*136 + cq*4] = hv;
        }
    }

    floatx4 Oa[2][8];
    #pragma unroll
    for (int mt=0;mt<2;mt++)
        #pragma unroll
        for (int nt=0;nt<8;nt++) Oa[mt][nt] = (floatx4){0.f,0.f,0.f,0.f};

    const floatx4 zc = (floatx4){0.f,0.f,0.f,0.f};
    const short8 z8 = {0,0,0,0,0,0,0,0};

    for (int h=0; h<8; h++){
        // ---- phase 2: QKV GEMM for n-tiles {3h, 3h+1, 3h+2} = q,k,v of head h
        floatx4 qacc[2][3];
        #pragma unroll
        for (int mt=0;mt<2;mt++)
            #pragma unroll
            for (int t=0;t<3;t++) qacc[mt][t] = zc;
        #pragma unroll
        for (int kc=0;kc<4;kc++){
            short8 af[2];
            #pragma unroll
            for (int mt=0;mt<2;mt++)
                af[mt] = *(const short8*)&lds[XO + (w*32+mt*16+lm)*136 + kc*32 + quad*8];
            #pragma unroll
            for (int t=0;t<3;t++){
                int nt = 3*h + t;
                short8 bf = *(const short8*)&Winp[(long)((nt*4+kc)*64 + L)*8];
                #pragma unroll
                for (int mt=0;mt<2;mt++)
                    qacc[mt][t] = __builtin_amdgcn_mfma_f32_16x16x32_bf16(af[mt], bf, qacc[mt][t], 0,0,0);
            }
        }
        // epilogue: Q,K -> plain [m][d]; V -> V^T [d][m]
        #pragma unroll
        for (int mt=0;mt<2;mt++){
            int m0 = w*32 + mt*16;
            #pragma unroll
            for (int r=0;r<4;r++){
                lds[QO + (m0+quad*4+r)*24 + lm] = (short)f2bf(qacc[mt][0][r]);
                lds[KO + (m0+quad*4+r)*24 + lm] = (short)f2bf(qacc[mt][1][r]);
            }
            short4v vv;
            #pragma unroll
            for (int r=0;r<4;r++) vv[r] = (short)f2bf(qacc[mt][2][r]);
            *(short4v*)&lds[VO + lm*136 + m0 + quad*4] = vv;
        }

        // ---- phase 3: per-site scores -> softmax -> PV ----
        #pragma unroll
        for (int mt=0;mt<2;mt++){
            int sb = w*32 + mt*16;
            short8 qf = z8, kf = z8;
            if (quad < 2){
                qf = *(const short8*)&lds[QO + (sb+lm)*24 + quad*8];
                kf = *(const short8*)&lds[KO + (sb+lm)*24 + quad*8];
            }
            floatx4 scv = __builtin_amdgcn_mfma_f32_16x16x32_bf16(qf, kf, zc, 0,0,0);
            float pv[4], mr[4];
            #pragma unroll
            for (int r=0;r<4;r++){
                int si = quad*4 + r;
                pv[r] = scv[r]*0.25f + (lm <= si ? 1.0f : -1000.0f);
                mr[r] = pv[r];
            }
            #pragma unroll
            for (int d=1; d<16; d<<=1)
                #pragma unroll
                for (int r=0;r<4;r++) mr[r] = fmaxf(mr[r], __shfl_xor(mr[r], d));
            float ex[4], sm[4];
            #pragma unroll
            for (int r=0;r<4;r++){ ex[r] = __expf(pv[r]-mr[r]); sm[r] = ex[r]; }
            #pragma unroll
            for (int d=1; d<16; d<<=1)
                #pragma unroll
                for (int r=0;r<4;r++) sm[r] += __shfl_xor(sm[r], d);
            #pragma unroll
            for (int r=0;r<4;r++)
                lds[PO + (sb+quad*4+r)*24 + lm] = (short)f2bf(ex[r]/sm[r]);

            short8 pf = z8, vf = z8;
            if (quad < 2){
                pf = *(const short8*)&lds[PO + (sb+lm)*24 + quad*8];
                vf = *(const short8*)&lds[VO + lm*136 + sb + quad*8];
            }
            floatx4 aov = __builtin_amdgcn_mfma_f32_16x16x32_bf16(pf, vf, zc, 0,0,0);
            #pragma unroll
            for (int r=0;r<4;r++)
                lds[AOO + (sb+quad*4+r)*24 + lm] = (short)f2bf(aov[r]);
        }

        // ---- phase 4: O += ao_h @ Wout[h-rows] ----
        #pragma unroll
        for (int mt=0;mt<2;mt++){
            short8 aof = z8;
            if (quad < 2)
                aof = *(const short8*)&lds[AOO + (w*32+mt*16+lm)*24 + quad*8];
            #pragma unroll
            for (int nt=0;nt<8;nt++){
                short8 wf = *(const short8*)&Woutp[(long)((h*8+nt)*64 + L)*8];
                Oa[mt][nt] = __builtin_amdgcn_mfma_f32_16x16x32_bf16(aof, wf, Oa[mt][nt], 0,0,0);
            }
        }
    }

    // epilogue: O + residual -> Y (in place over X rows this block loaded)
    #pragma unroll
    for (int mt=0;mt<2;mt++){
        int hw = hw0 + w*2 + mt;
        #pragma unroll
        for (int nt=0;nt<8;nt++){
            int n = nt*16 + lm;
            #pragma unroll
            for (int r=0;r<4;r++){
                int s = quad*4 + r;
                long addr = (((long)b*16 + s)*1024 + hw)*128 + n;
                Y[addr] = Oa[mt][nt][r] + resid[addr];
            }
        }
    }
}

// ---------------------------------------------------------------------------
// Weights -> B-fragment packets, bf16 (conv GEMM).
__global__ __launch_bounds__(256)
void k_pack_w(const float* __restrict__ ck, short* __restrict__ Bp){
    int p = blockIdx.x*256 + threadIdx.x;     // 147456 exact
    int L = p & 63;
    int nt = (p >> 6) & 31;
    int c32 = (p >> 11) & 7;
    int tap = p >> 14;
    int oc = nt*16 + (L & 15);
    int kq = L >> 4;
    short8 v;
    #pragma unroll
    for (int j=0;j<8;j++){
        int ic = c32*32 + kq*8 + j;
        v[j] = (short)f2bf(ck[(oc*256+ic)*9 + tap]);
    }
    *(short8*)&Bp[(long)p*8] = v;
}

// ---------------------------------------------------------------------------
// Pack X slice s (fp32) -> bf16 x-half of xh[row][0:128]; zero h-half at s==0
// (only used once for s=0; the lstm kernel packs slices 1..15 inline)
__global__ __launch_bounds__(256)
void k_pack_x(const float* __restrict__ X, short* __restrict__ xh, int s, int zero_h){
    int idx = blockIdx.x*256 + threadIdx.x;   // 131072
    int row = idx >> 4;
    int ch = (idx & 15) * 8;
    int b = row >> 10, hw = row & 1023;
    const float* src = X + (((long)(b*16+s)*1024 + hw)*128 + ch);
    float4 a = *(const float4*)src;
    float4 c = *(const float4*)(src+4);
    short8 v;
    v[0]=(short)f2bf(a.x); v[1]=(short)f2bf(a.y); v[2]=(short)f2bf(a.z); v[3]=(short)f2bf(a.w);
    v[4]=(short)f2bf(c.x); v[5]=(short)f2bf(c.y); v[6]=(short)f2bf(c.z); v[7]=(short)f2bf(c.w);
    *(short8*)&xh[(long)row*256 + ch] = v;
    if (zero_h){
        short8 z = {0,0,0,0,0,0,0,0};
        *(short8*)&xh[(long)row*256 + 128 + ch] = z;
    }
}

// ---------------------------------------------------------------------------
// Implicit-im2col MFMA GEMM: gates[8192][512] = patches(xh) @ W.
// (R5 variant — best measured. Block 512 thr x Ntile 256 x Mtile 64, grid
// 256; halo staged once, barrier-free K-loop, batched staging loads.)
template<typename GT>
__global__ __launch_bounds__(512,2)
void k_conv_mfma(const short* __restrict__ xh, const short* __restrict__ Bp,
                 GT* __restrict__ gbuf){
    __shared__ short As[4*34*264];           // 71,808 B
    int tid = threadIdx.x;
    int Nblk = blockIdx.x & 1, g = blockIdx.x >> 1;      // g 0..127
    int b = g >> 4, y0 = (g & 15)*2;
    int w = tid >> 6, L = tid & 63;
    int quad = L >> 4, lm = L & 15;
    int wm = w >> 2, wn = w & 3;             // wave -> (m-pair, n-quad)
    int ntg = Nblk*16 + wn*4;                // first of this wave's 4 n-tiles

    // ---- stage A halo: rows y0-1..y0+2, x -1..32, ch 0..255 (zero-padded)
    const short8 z8 = {0,0,0,0,0,0,0,0};
    {
        short8 vs[9];
        #pragma unroll
        for (int i=0; i<9; i++){
            int pidx = i*512 + tid;
            short8 v = z8;
            if (pidx < 4352){
                int cb  = pidx & 31;             // 8-ch granule
                int pos = pidx >> 5;             // row*34 + xp
                int row = pos / 34;
                int xp  = pos - row*34;
                int yy = y0 - 1 + row, xx = xp - 1;
                if (yy>=0 && yy<32 && xx>=0 && xx<32)
                    v = *(const short8*)&xh[(((long)(b*32+yy)*32+xx)<<8) + cb*8];
            }
            vs[i] = v;
        }
        #pragma unroll
        for (int i=0; i<9; i++){
            int pidx = i*512 + tid;
            if (pidx < 4352){
                int cb  = pidx & 31;
                int pos = pidx >> 5;
                *(short8*)&As[pos*264 + cb*8] = vs[i];
            }
        }
    }
    __syncthreads();

    floatx4 acc[2][4];
    #pragma unroll
    for (int mtl=0;mtl<2;mtl++)
        #pragma unroll
        for (int nti=0;nti<4;nti++)
            acc[mtl][nti] = (floatx4){0.f,0.f,0.f,0.f};

    const short8* Bp8 = (const short8*)Bp;

    for (int tap=0; tap<9; tap++){
        int dy = tap/3 - 1, dx = tap - (tap/3)*3 - 1;
        int abase[2];
        #pragma unroll
        for (int mtl=0;mtl<2;mtl++){
            int x = mtl*16 + lm;
            abase[mtl] = (((wm+dy+1)*34) + x + dx + 1)*264 + quad*8;
        }
        #pragma unroll
        for (int sic=0; sic<4; sic++){
            #pragma unroll
            for (int c2=0; c2<2; c2++){
                short8 bfr[4];
                #pragma unroll
                for (int nti=0;nti<4;nti++)
                    bfr[nti] = Bp8[((tap*8 + sic*2 + c2)*32 + ntg + nti)*64 + L];
                #pragma unroll
                for (int mtl=0;mtl<2;mtl++){
                    short8 afr = *(const short8*)&As[abase[mtl] + sic*64 + c2*32];
                    #pragma unroll
                    for (int nti=0;nti<4;nti++)
                        acc[mtl][nti] = __builtin_amdgcn_mfma_f32_16x16x32_bf16(afr, bfr[nti], acc[mtl][nti], 0,0,0);
                }
            }
        }
    }

    #pragma unroll
    for (int mtl=0;mtl<2;mtl++){
        #pragma unroll
        for (int nti=0;nti<4;nti++){
            int n = Nblk*256 + (wn*4+nti)*16 + lm;
            #pragma unroll
            for (int r=0;r<4;r++){
                long row = (long)g*64 + (wm*2+mtl)*16 + quad*4 + r;
                st_gate(&gbuf[row*512 + n], acc[mtl][nti][r]);
            }
        }
    }
}

// ---------------------------------------------------------------------------
// Fused LSTM pointwise + inline pack of next slice's x-half (replaces k_pack_x
// for s=1..15: X is fixed after attention, and lstm already touches every
// (row, c4), so packing here saves a dependent launch per step)
template<typename GT>
__global__ __launch_bounds__(256)
void k_lstm(const GT* __restrict__ gbuf, float* __restrict__ cbuf,
            float* __restrict__ X, short* __restrict__ xh, int s){
    int idx = blockIdx.x*256 + threadIdx.x;    // 262144
    int row = idx >> 5;
    int c4 = (idx & 31)*4;
    float gi[4], gf[4], go[4], gg[4];
    const GT* gp = gbuf + (long)row*512 + c4;
    load_gate(gp,       gi);
    load_gate(gp + 128, gf);
    load_gate(gp + 256, go);
    load_gate(gp + 384, gg);
    float co[4];
    if (s == 0){ co[0]=co[1]=co[2]=co[3]=0.f; }
    else {
        float4 cv = *(const float4*)&cbuf[(long)row*128 + c4];
        co[0]=cv.x; co[1]=cv.y; co[2]=cv.z; co[3]=cv.w;
    }
    float cn[4], hn[4];
    #pragma unroll
    for (int j=0;j<4;j++){
        cn[j] = sigf(gf[j])*co[j] + sigf(gi[j])*tanh_fast(gg[j]);
        hn[j] = sigf(go[j])*tanh_fast(cn[j]);
    }
    *(float4*)&cbuf[(long)row*128 + c4] = make_float4(cn[0],cn[1],cn[2],cn[3]);
    int b = row >> 10, hw = row & 1023;
    long xoff = (((long)(b*16+s)*1024 + hw)*128) + c4;
    *(float4*)&X[xoff] = make_float4(hn[0],hn[1],hn[2],hn[3]);
    ushort4 hv;
    hv.x = f2bf(hn[0]); hv.y = f2bf(hn[1]); hv.z = f2bf(hn[2]); hv.w = f2bf(hn[3]);
    *(ushort4*)&xh[(long)row*256 + 128 + c4] = hv;
    // pack next slice's x-half (attn output slice s+1 is untouched: lstm steps
    // only overwrite their own slice, ascending)
    if (s < 15){
        long x2 = (((long)(b*16+s+1)*1024 + hw)*128) + c4;
        float4 xv = *(const float4*)&X[x2];
        ushort4 xb;
        xb.x = f2bf(xv.x); xb.y = f2bf(xv.y); xb.z = f2bf(xv.z); xb.w = f2bf(xv.w);
        *(ushort4*)&xh[(long)row*256 + c4] = xb;
    }
}

// ---------------------------------------------------------------------------
extern "C" void kernel_launch(void* const* d_in, const int* in_sizes, int n_in,
                              void* d_out, int out_size, void* d_ws, size_t ws_size,
                              hipStream_t stream){
    const float* inputs = (const float*)d_in[0];
    const float* Wp     = (const float*)d_in[1];
    const float* gamma  = (const float*)d_in[2];
    const float* beta   = (const float*)d_in[3];
    const float* Win    = (const float*)d_in[4];
    const float* Wout   = (const float*)d_in[5];
    const float* ck     = (const float*)d_in[6];
    float* X = (float*)d_out;

    char* ws = (char*)d_ws;
    const size_t szB    = 147456ull*16;        // 2,359,296
    const size_t szXH   = 8192ull*256*2;       // 4,194,304
    const size_t szC    = 8192ull*128*4;       // 4,194,304
    const size_t szWin  = 6144ull*16;          //    98,304
    const size_t szWout = 4096ull*16;          //    65,536
    short* Bp    = (short*)(ws);
    short* xh    = (short*)(ws + szB);
    float* cbuf  = (float*)(ws + szB + szXH);
    short* Winp  = (short*)(ws + szB + szXH + szC);
    short* Woutp = (short*)(ws + szB + szXH + szC + szWin);
    char*  gch   =         ws + szB + szXH + szC + szWin + szWout;
    bool gate_f32 = ws_size >= (szB + szXH + szC + szWin + szWout + 8192ull*512*4);
    // W_proj split-bf16 packets (98,304 B) alias the gbuf region: consumed by
    // k_proj_ln_mfma before the scan loop's first k_conv_mfma write to gbuf.
    short* Wprojp = (short*)gch;

    k_pack_w<<<576, 256, 0, stream>>>(ck, Bp);
    k_pack_win<<<24, 256, 0, stream>>>(Win, Winp);
    k_pack_wout<<<16, 256, 0, stream>>>(Wout, Woutp);
    k_pack_wproj<<<24, 256, 0, stream>>>(Wp, Wprojp);
    k_proj_ln_mfma<<<NTOK/64, 256, 0, stream>>>(inputs, Wprojp, gamma, beta, X);
    k_attn_mfma<<<1024, 256, 0, stream>>>(X, Winp, Woutp, inputs, X);  // in-place
    k_pack_x<<<512, 256, 0, stream>>>(X, xh, 0, 1);

    if (gate_f32){
        float* gbuf = (float*)gch;
        for (int s=0; s<16; s++){
            k_conv_mfma<float><<<256, 512, 0, stream>>>(xh, Bp, gbuf);
            k_lstm<float><<<1024, 256, 0, stream>>>(gbuf, cbuf, X, xh, s);
        }
    } else {
        unsigned short* gbuf = (unsigned short*)gch;
        for (int s=0; s<16; s++){
            k_conv_mfma<unsigned short><<<256, 512, 0, stream>>>(xh, Bp, gbuf);
            k_lstm<unsigned short><<<1024, 256, 0, stream>>>(gbuf, cbuf, X, xh, s);
        }
    }
}

// Round 8
// 859.685 us; speedup vs baseline: 1.0222x; 1.0045x over previous
//
#include <hip/hip_runtime.h>
#include <math.h>

#define B_  8
#define S_  16
#define H_  32
#define W_  32
#define E_  128
#define NH_ 8
#define HD_ 16
#define HW_ (H_*W_)            // 1024
#define NTOK (B_*S_*H_*W_)     // 131072

typedef __attribute__((ext_vector_type(8))) short short8;
typedef __attribute__((ext_vector_type(4))) short short4v;
typedef __attribute__((ext_vector_type(4))) float floatx4;

__device__ __forceinline__ float sigf(float x){
    return 1.f/(1.f+__expf(-x));
}
__device__ __forceinline__ float tanh_fast(float x){
    x = fminf(fmaxf(x, -15.f), 15.f);
    float e = __expf(2.f*x);
    return (e-1.f)/(e+1.f);
}
__device__ __forceinline__ unsigned short f2bf(float f){
    unsigned int u = __float_as_uint(f);
    u = (u + 0x7fffu + ((u >> 16) & 1u)) >> 16;   // RNE
    return (unsigned short)u;
}
__device__ __forceinline__ float bf2f(unsigned short h){
    return __uint_as_float(((unsigned int)h) << 16);
}

__device__ __forceinline__ void st_gate(float* p, float v){ *p = v; }
__device__ __forceinline__ void st_gate(unsigned short* p, float v){ *p = f2bf(v); }
__device__ __forceinline__ void load_gate(const float* p, float* o){
    float4 v = *(const float4*)p; o[0]=v.x; o[1]=v.y; o[2]=v.z; o[3]=v.w;
}
__device__ __forceinline__ void load_gate(const unsigned short* p, float* o){
    ushort4 v = *(const ushort4*)p;
    o[0]=bf2f(v.x); o[1]=bf2f(v.y); o[2]=bf2f(v.z); o[3]=bf2f(v.w);
}

// ---------------------------------------------------------------------------
// W_proj (128x128 fp32) -> split-bf16 B' fragments for K=384 GEMM.
__global__ __launch_bounds__(256)
void k_pack_wproj(const float* __restrict__ Wp, short* __restrict__ Wpp){
    int p = blockIdx.x*256 + threadIdx.x;    // 6144 packets
    int L = p & 63;
    int idx = p >> 6;                        // nt*12 + kb
    int nt = idx / 12, kb = idx - nt*12;
    int n = nt*16 + (L & 15);
    int kr = (kb & 3)*32 + (L >> 4)*8;
    bool lo = (kb >= 8);
    short8 v;
    #pragma unroll
    for (int j=0;j<8;j++){
        float wv = Wp[(kr+j)*128 + n];
        unsigned short h = f2bf(wv);
        v[j] = lo ? (short)f2bf(wv - bf2f(h)) : (short)h;
    }
    *(short8*)&Wpp[(long)p*8] = v;
}

// ---------------------------------------------------------------------------
// X = LayerNorm(silu(inputs @ W_proj)) via split-bf16 MFMA (fp32-accurate).
// R7 layout: wave = 4 m-tiles x 2 n-tiles (B per wave 24 KB); LN row-sums
// cross waves via LDS red[] + barrier.
__global__ __launch_bounds__(256,4)
void k_proj_ln_mfma(const float* __restrict__ in, const short* __restrict__ Wpp,
                    const float* __restrict__ gamma, const float* __restrict__ beta,
                    float* __restrict__ X){
    __shared__ short As[64*264];             // 33,792 B
    __shared__ float red[4][64][2];          //  2,048 B
    int tid = threadIdx.x;
    int w = tid >> 6, L = tid & 63;
    int quad = L >> 4, lm = L & 15;
    long r0 = (long)blockIdx.x * 64;

    // stage: 64 rows x 128 f32 -> split bf16 (coalesced float4 loads)
    {
        int c = (tid & 31)*4;
        int rbase = tid >> 5;
        #pragma unroll
        for (int rr=0; rr<8; rr++){
            int r = rr*8 + rbase;
            float4 v = *(const float4*)&in[(r0 + r)*128 + c];
            short4v hv, lv;
            unsigned short h;
            h = f2bf(v.x); hv[0]=(short)h; lv[0]=(short)f2bf(v.x - bf2f(h));
            h = f2bf(v.y); hv[1]=(short)h; lv[1]=(short)f2bf(v.y - bf2f(h));
            h = f2bf(v.z); hv[2]=(short)h; lv[2]=(short)f2bf(v.z - bf2f(h));
            h = f2bf(v.w); hv[3]=(short)h; lv[3]=(short)f2bf(v.w - bf2f(h));
            *(short4v*)&As[r*264 + c] = hv;
            *(short4v*)&As[r*264 + 128 + c] = lv;
        }
    }
    __syncthreads();

    floatx4 acc[4][2];
    #pragma unroll
    for (int mtl=0;mtl<4;mtl++)
        #pragma unroll
        for (int nti=0;nti<2;nti++)
            acc[mtl][nti] = (floatx4){0.f,0.f,0.f,0.f};
    const short8* Bp8 = (const short8*)Wpp;
    #pragma unroll
    for (int kb=0; kb<12; kb++){
        int off = (kb<4) ? kb*32 : ((kb<8) ? 128+(kb-4)*32 : (kb-8)*32);
        short8 af[4];
        #pragma unroll
        for (int mtl=0;mtl<4;mtl++)
            af[mtl] = *(const short8*)&As[(mtl*16+lm)*264 + off + quad*8];
        #pragma unroll
        for (int nti=0;nti<2;nti++){
            short8 bf = Bp8[((2*w+nti)*12+kb)*64 + L];
            #pragma unroll
            for (int mtl=0;mtl<4;mtl++)
                acc[mtl][nti] = __builtin_amdgcn_mfma_f32_16x16x32_bf16(af[mtl], bf, acc[mtl][nti], 0,0,0);
        }
    }

    // fused silu + LayerNorm epilogue (cross-wave row reduction).
    #pragma unroll
    for (int mtl=0;mtl<4;mtl++){
        float p1[4]={0,0,0,0}, p2[4]={0,0,0,0};
        #pragma unroll
        for (int nti=0;nti<2;nti++)
            #pragma unroll
            for (int r=0;r<4;r++){
                float a = acc[mtl][nti][r];
                float si = a*sigf(a);             // silu
                acc[mtl][nti][r] = si;
                p1[r] += si; p2[r] += si*si;
            }
        #pragma unroll
        for (int d=1; d<16; d<<=1)
            #pragma unroll
            for (int r=0;r<4;r++){
                p1[r] += __shfl_xor(p1[r], d);
                p2[r] += __shfl_xor(p2[r], d);
            }
        if (lm == 0){
            #pragma unroll
            for (int r=0;r<4;r++){
                int row = mtl*16 + quad*4 + r;
                red[w][row][0] = p1[r];
                red[w][row][1] = p2[r];
            }
        }
    }
    __syncthreads();
    float g[2], bb[2];
    #pragma unroll
    for (int nti=0;nti<2;nti++){
        g[nti]  = gamma[(2*w+nti)*16 + lm];
        bb[nti] = beta [(2*w+nti)*16 + lm];
    }
    #pragma unroll
    for (int mtl=0;mtl<4;mtl++){
        #pragma unroll
        for (int r=0;r<4;r++){
            int row = mtl*16 + quad*4 + r;
            float s1 = red[0][row][0] + red[1][row][0] + red[2][row][0] + red[3][row][0];
            float s2 = red[0][row][1] + red[1][row][1] + red[2][row][1] + red[3][row][1];
            float mu  = s1 * (1.f/128.f);
            float var = s2 * (1.f/128.f) - mu*mu;
            float rs  = rsqrtf(var + 1e-5f);
            #pragma unroll
            for (int nti=0;nti<2;nti++)
                X[(r0+row)*128 + (2*w+nti)*16 + lm] = (acc[mtl][nti][r]-mu)*rs*g[nti] + bb[nti];
        }
    }
}

// ---------------------------------------------------------------------------
// W_in (128x384) -> bf16 B-fragment packets.
__global__ __launch_bounds__(256)
void k_pack_win(const float* __restrict__ Win, short* __restrict__ Winp){
    int p = blockIdx.x*256 + threadIdx.x;    // 6144 packets
    int L = p & 63;
    int idx = p >> 6;                        // nt*4+kc
    int nt = idx >> 2, kc = idx & 3;
    int n = nt*16 + (L & 15);
    int k0 = kc*32 + (L >> 4)*8;
    short8 v;
    #pragma unroll
    for (int j=0;j<8;j++) v[j] = (short)f2bf(Win[(k0+j)*384 + n]);
    *(short8*)&Winp[(long)p*8] = v;
}

// ---------------------------------------------------------------------------
// W_out (128x128) -> per-head zero-padded B packets.
__global__ __launch_bounds__(256)
void k_pack_wout(const float* __restrict__ Wout, short* __restrict__ Woutp){
    int p = blockIdx.x*256 + threadIdx.x;    // 4096 packets
    int L = p & 63;
    int idx = p >> 6;                        // h*8+nt
    int h = idx >> 3, nt = idx & 7;
    int n = nt*16 + (L & 15);
    int k0 = (L >> 4)*8;
    short8 v;
    #pragma unroll
    for (int j=0;j<8;j++){
        int k = k0 + j;
        v[j] = (k < 16) ? (short)f2bf(Wout[(h*16+k)*128 + n]) : (short)0;
    }
    *(short8*)&Woutp[(long)p*8] = v;
}

// ---------------------------------------------------------------------------
// Fused MFMA attention. R8 = revert to the R6 4-site version (77 us, 41% occ)
// — R7's 2-site variant regressed to 87 us (LDS 51.5 KB -> occupancy 23%).
// Block = (b, 4 hw-sites), 4 waves, each owns ONE site; wave-local LDS.
__global__ __launch_bounds__(256,5)
void k_attn_mfma(const float* __restrict__ X, const short* __restrict__ Winp,
                 const short* __restrict__ Woutp, const float* __restrict__ resid,
                 float* __restrict__ Y){
    __shared__ short lds[16000];             // 32,000 B
    const int XO=0;                          // X tile  [64][136]
    const int QO=8704;                       // Q plain [64][24]
    const int KO=10240;                      // K plain [64][24]
    const int VO=11776;                      // V^T     [16][72] (cols = m)
    const int PO=12928;                      // P plain [64][24]
    const int AOO=14464;                     // ao      [64][24]
    int tid = threadIdx.x;
    int w = tid >> 6, L = tid & 63;
    int quad = L >> 4, lm = L & 15;
    int b = blockIdx.x >> 8, tile = blockIdx.x & 255;
    int hw0 = tile * 4;
    int hw = hw0 + w;                        // this wave's site

    // phase 1: wave-local X rows w*16..w*16+15 (site w), fp32->bf16
    {
        int cq = L & 31, rh = L >> 5;
        for (int p=0; p<8; p++){
            int m = w*16 + p*2 + rh;
            int s = m & 15;
            float4 v = *(const float4*)&X[((((long)b*16 + s)*1024) + hw)*128 + cq*4];
            short4v hv;
            hv[0]=(short)f2bf(v.x); hv[1]=(short)f2bf(v.y);
            hv[2]=(short)f2bf(v.z); hv[3]=(short)f2bf(v.w);
            *(short4v*)&lds[XO + m*136 + cq*4] = hv;
        }
    }

    floatx4 Oa[8];
    #pragma unroll
    for (int nt=0;nt<8;nt++) Oa[nt] = (floatx4){0.f,0.f,0.f,0.f};

    const floatx4 zc = (floatx4){0.f,0.f,0.f,0.f};
    const short8 z8 = {0,0,0,0,0,0,0,0};
    int m0 = w*16;

    for (int h=0; h<8; h++){
        // ---- phase 2: QKV GEMM for n-tiles {3h, 3h+1, 3h+2} = q,k,v of head h
        floatx4 qacc[3];
        #pragma unroll
        for (int t=0;t<3;t++) qacc[t] = zc;
        #pragma unroll
        for (int kc=0;kc<4;kc++){
            short8 af = *(const short8*)&lds[XO + (m0+lm)*136 + kc*32 + quad*8];
            #pragma unroll
            for (int t=0;t<3;t++){
                int nt = 3*h + t;
                short8 bf = *(const short8*)&Winp[(long)((nt*4+kc)*64 + L)*8];
                qacc[t] = __builtin_amdgcn_mfma_f32_16x16x32_bf16(af, bf, qacc[t], 0,0,0);
            }
        }
        // epilogue: Q,K -> plain [m][d]; V -> V^T [d][m]
        #pragma unroll
        for (int r=0;r<4;r++){
            lds[QO + (m0+quad*4+r)*24 + lm] = (short)f2bf(qacc[0][r]);
            lds[KO + (m0+quad*4+r)*24 + lm] = (short)f2bf(qacc[1][r]);
        }
        {
            short4v vv;
            #pragma unroll
            for (int r=0;r<4;r++) vv[r] = (short)f2bf(qacc[2][r]);
            *(short4v*)&lds[VO + lm*72 + m0 + quad*4] = vv;
        }

        // ---- phase 3: per-site scores -> softmax -> PV ----
        {
            short8 qf = z8, kf = z8;
            if (quad < 2){
                qf = *(const short8*)&lds[QO + (m0+lm)*24 + quad*8];
                kf = *(const short8*)&lds[KO + (m0+lm)*24 + quad*8];
            }
            floatx4 scv = __builtin_amdgcn_mfma_f32_16x16x32_bf16(qf, kf, zc, 0,0,0);
            float pv[4], mr[4];
            #pragma unroll
            for (int r=0;r<4;r++){
                int si = quad*4 + r;
                pv[r] = scv[r]*0.25f + (lm <= si ? 1.0f : -1000.0f);
                mr[r] = pv[r];
            }
            #pragma unroll
            for (int d=1; d<16; d<<=1)
                #pragma unroll
                for (int r=0;r<4;r++) mr[r] = fmaxf(mr[r], __shfl_xor(mr[r], d));
            float ex[4], sm[4];
            #pragma unroll
            for (int r=0;r<4;r++){ ex[r] = __expf(pv[r]-mr[r]); sm[r] = ex[r]; }
            #pragma unroll
            for (int d=1; d<16; d<<=1)
                #pragma unroll
                for (int r=0;r<4;r++) sm[r] += __shfl_xor(sm[r], d);
            #pragma unroll
            for (int r=0;r<4;r++)
                lds[PO + (m0+quad*4+r)*24 + lm] = (short)f2bf(ex[r]/sm[r]);

            short8 pf = z8, vf = z8;
            if (quad < 2){
                pf = *(const short8*)&lds[PO + (m0+lm)*24 + quad*8];
                vf = *(const short8*)&lds[VO + lm*72 + m0 + quad*8];
            }
            floatx4 aov = __builtin_amdgcn_mfma_f32_16x16x32_bf16(pf, vf, zc, 0,0,0);
            #pragma unroll
            for (int r=0;r<4;r++)
                lds[AOO + (m0+quad*4+r)*24 + lm] = (short)f2bf(aov[r]);
        }

        // ---- phase 4: O += ao_h @ Wout[h-rows] ----
        {
            short8 aof = z8;
            if (quad < 2)
                aof = *(const short8*)&lds[AOO + (m0+lm)*24 + quad*8];
            #pragma unroll
            for (int nt=0;nt<8;nt++){
                short8 wf = *(const short8*)&Woutp[(long)((h*8+nt)*64 + L)*8];
                Oa[nt] = __builtin_amdgcn_mfma_f32_16x16x32_bf16(aof, wf, Oa[nt], 0,0,0);
            }
        }
    }

    // epilogue: O + residual -> Y (in place over X rows this block loaded)
    #pragma unroll
    for (int nt=0;nt<8;nt++){
        int n = nt*16 + lm;
        #pragma unroll
        for (int r=0;r<4;r++){
            int s = quad*4 + r;
            long addr = (((long)b*16 + s)*1024 + hw)*128 + n;
            Y[addr] = Oa[nt][r] + resid[addr];
        }
    }
}

// ---------------------------------------------------------------------------
// Weights -> B-fragment packets, bf16 (conv GEMM).
__global__ __launch_bounds__(256)
void k_pack_w(const float* __restrict__ ck, short* __restrict__ Bp){
    int p = blockIdx.x*256 + threadIdx.x;     // 147456 exact
    int L = p & 63;
    int nt = (p >> 6) & 31;
    int c32 = (p >> 11) & 7;
    int tap = p >> 14;
    int oc = nt*16 + (L & 15);
    int kq = L >> 4;
    short8 v;
    #pragma unroll
    for (int j=0;j<8;j++){
        int ic = c32*32 + kq*8 + j;
        v[j] = (short)f2bf(ck[(oc*256+ic)*9 + tap]);
    }
    *(short8*)&Bp[(long)p*8] = v;
}

// ---------------------------------------------------------------------------
// Pack X slice s (fp32) -> bf16 x-half of xh[row][0:128]; zero h-half at s==0
__global__ __launch_bounds__(256)
void k_pack_x(const float* __restrict__ X, short* __restrict__ xh, int s, int zero_h){
    int idx = blockIdx.x*256 + threadIdx.x;   // 131072
    int row = idx >> 4;
    int ch = (idx & 15) * 8;
    int b = row >> 10, hw = row & 1023;
    const float* src = X + (((long)(b*16+s)*1024 + hw)*128 + ch);
    float4 a = *(const float4*)src;
    float4 c = *(const float4*)(src+4);
    short8 v;
    v[0]=(short)f2bf(a.x); v[1]=(short)f2bf(a.y); v[2]=(short)f2bf(a.z); v[3]=(short)f2bf(a.w);
    v[4]=(short)f2bf(c.x); v[5]=(short)f2bf(c.y); v[6]=(short)f2bf(c.z); v[7]=(short)f2bf(c.w);
    *(short8*)&xh[(long)row*256 + ch] = v;
    if (zero_h){
        short8 z = {0,0,0,0,0,0,0,0};
        *(short8*)&xh[(long)row*256 + 128 + ch] = z;
    }
}

// ---------------------------------------------------------------------------
// Implicit-im2col MFMA GEMM: gates[8192][512] = patches(xh) @ W.
// R8 rework: all prior structures plateaued ~36-40 us because the B stream
// (302-604 MB/dispatch) came from Infinity Cache (~10 TB/s) — L2 is churned
// by gbuf/xh. Cut B traffic instead of re-shuffling overlap:
//  (1) Mtile 128 (4 image rows/block): B traffic = 19.3GB/Mtile -> 151 MB.
//      Halo = 6 rows x 34 x 256ch in LDS (107,712 B), grid 64x4=256 blocks,
//      512 thr, barrier-free K-loop.
//  (2) XCD-aligned N-split: blockIdx->XCD is %8 round-robin (m09), so
//      Nblk = blockIdx&3 is CONSTANT per XCD -> per-XCD B working set is one
//      590 KB quarter, L2-resident. (If mapping differs: only speed changes.)
// Accumulation order (tap,sic,c2) unchanged -> bit-identical gbuf.
template<typename GT>
__global__ __launch_bounds__(512,2)
void k_conv_mfma(const short* __restrict__ xh, const short* __restrict__ Bp,
                 GT* __restrict__ gbuf){
    __shared__ short As[6*34*264];           // 107,712 B
    int tid = threadIdx.x;
    int Nblk = blockIdx.x & 3, g = blockIdx.x >> 2;      // g 0..63
    int b = g >> 3, y0 = (g & 7)*4;
    int w = tid >> 6, L = tid & 63;
    int quad = L >> 4, lm = L & 15;
    int wm = w >> 1, wn = w & 1;             // wave -> (m-row, n-half)
    int ntg = Nblk*8 + wn*4;                 // first of this wave's 4 n-tiles

    // ---- stage A halo: rows y0-1..y0+4, x -1..32, ch 0..255 (zero-padded)
    // 6528 packets in 13 rounds of 512; loads batched to regs, then stores.
    const short8 z8 = {0,0,0,0,0,0,0,0};
    {
        short8 vs[13];
        #pragma unroll
        for (int i=0; i<13; i++){
            int pidx = i*512 + tid;
            short8 v = z8;
            if (pidx < 6528){
                int cb  = pidx & 31;             // 8-ch granule
                int pos = pidx >> 5;             // row*34 + xp
                int row = pos / 34;
                int xp  = pos - row*34;
                int yy = y0 - 1 + row, xx = xp - 1;
                if (yy>=0 && yy<32 && xx>=0 && xx<32)
                    v = *(const short8*)&xh[(((long)(b*32+yy)*32+xx)<<8) + cb*8];
            }
            vs[i] = v;
        }
        #pragma unroll
        for (int i=0; i<13; i++){
            int pidx = i*512 + tid;
            if (pidx < 6528){
                int cb  = pidx & 31;
                int pos = pidx >> 5;
                *(short8*)&As[pos*264 + cb*8] = vs[i];
            }
        }
    }
    __syncthreads();

    floatx4 acc[2][4];
    #pragma unroll
    for (int mtl=0;mtl<2;mtl++)
        #pragma unroll
        for (int nti=0;nti<4;nti++)
            acc[mtl][nti] = (floatx4){0.f,0.f,0.f,0.f};

    const short8* Bp8 = (const short8*)Bp;

    for (int tap=0; tap<9; tap++){
        int dy = tap/3 - 1, dx = tap - (tap/3)*3 - 1;
        // wave wm owns image row ys=wm (of 4); m-tiles wm*2+mtl, x = mtl*16+lm
        int abase[2];
        #pragma unroll
        for (int mtl=0;mtl<2;mtl++){
            int x = mtl*16 + lm;
            abase[mtl] = (((wm+dy+1)*34) + x + dx + 1)*264 + quad*8;
        }
        #pragma unroll
        for (int sic=0; sic<4; sic++){
            #pragma unroll
            for (int c2=0; c2<2; c2++){
                short8 bfr[4];
                #pragma unroll
                for (int nti=0;nti<4;nti++)
                    bfr[nti] = Bp8[((tap*8 + sic*2 + c2)*32 + ntg + nti)*64 + L];
                #pragma unroll
                for (int mtl=0;mtl<2;mtl++){
                    short8 afr = *(const short8*)&As[abase[mtl] + sic*64 + c2*32];
                    #pragma unroll
                    for (int nti=0;nti<4;nti++)
                        acc[mtl][nti] = __builtin_amdgcn_mfma_f32_16x16x32_bf16(afr, bfr[nti], acc[mtl][nti], 0,0,0);
                }
            }
        }
    }

    #pragma unroll
    for (int mtl=0;mtl<2;mtl++){
        #pragma unroll
        for (int nti=0;nti<4;nti++){
            int n = Nblk*128 + (wn*4+nti)*16 + lm;
            #pragma unroll
            for (int r=0;r<4;r++){
                long row = (long)g*128 + wm*32 + mtl*16 + quad*4 + r;
                st_gate(&gbuf[row*512 + n], acc[mtl][nti][r]);
            }
        }
    }
}

// ---------------------------------------------------------------------------
// Fused LSTM pointwise + inline pack of next slice's x-half.
template<typename GT>
__global__ __launch_bounds__(256)
void k_lstm(const GT* __restrict__ gbuf, float* __restrict__ cbuf,
            float* __restrict__ X, short* __restrict__ xh, int s){
    int idx = blockIdx.x*256 + threadIdx.x;    // 262144
    int row = idx >> 5;
    int c4 = (idx & 31)*4;
    float gi[4], gf[4], go[4], gg[4];
    const GT* gp = gbuf + (long)row*512 + c4;
    load_gate(gp,       gi);
    load_gate(gp + 128, gf);
    load_gate(gp + 256, go);
    load_gate(gp + 384, gg);
    float co[4];
    if (s == 0){ co[0]=co[1]=co[2]=co[3]=0.f; }
    else {
        float4 cv = *(const float4*)&cbuf[(long)row*128 + c4];
        co[0]=cv.x; co[1]=cv.y; co[2]=cv.z; co[3]=cv.w;
    }
    float cn[4], hn[4];
    #pragma unroll
    for (int j=0;j<4;j++){
        cn[j] = sigf(gf[j])*co[j] + sigf(gi[j])*tanh_fast(gg[j]);
        hn[j] = sigf(go[j])*tanh_fast(cn[j]);
    }
    *(float4*)&cbuf[(long)row*128 + c4] = make_float4(cn[0],cn[1],cn[2],cn[3]);
    int b = row >> 10, hw = row & 1023;
    long xoff = (((long)(b*16+s)*1024 + hw)*128) + c4;
    *(float4*)&X[xoff] = make_float4(hn[0],hn[1],hn[2],hn[3]);
    ushort4 hv;
    hv.x = f2bf(hn[0]); hv.y = f2bf(hn[1]); hv.z = f2bf(hn[2]); hv.w = f2bf(hn[3]);
    *(ushort4*)&xh[(long)row*256 + 128 + c4] = hv;
    if (s < 15){
        long x2 = (((long)(b*16+s+1)*1024 + hw)*128) + c4;
        float4 xv = *(const float4*)&X[x2];
        ushort4 xb;
        xb.x = f2bf(xv.x); xb.y = f2bf(xv.y); xb.z = f2bf(xv.z); xb.w = f2bf(xv.w);
        *(ushort4*)&xh[(long)row*256 + c4] = xb;
    }
}

// ---------------------------------------------------------------------------
extern "C" void kernel_launch(void* const* d_in, const int* in_sizes, int n_in,
                              void* d_out, int out_size, void* d_ws, size_t ws_size,
                              hipStream_t stream){
    const float* inputs = (const float*)d_in[0];
    const float* Wp     = (const float*)d_in[1];
    const float* gamma  = (const float*)d_in[2];
    const float* beta   = (const float*)d_in[3];
    const float* Win    = (const float*)d_in[4];
    const float* Wout   = (const float*)d_in[5];
    const float* ck     = (const float*)d_in[6];
    float* X = (float*)d_out;

    char* ws = (char*)d_ws;
    const size_t szB    = 147456ull*16;        // 2,359,296
    const size_t szXH   = 8192ull*256*2;       // 4,194,304
    const size_t szC    = 8192ull*128*4;       // 4,194,304
    const size_t szWin  = 6144ull*16;          //    98,304
    const size_t szWout = 4096ull*16;          //    65,536
    short* Bp    = (short*)(ws);
    short* xh    = (short*)(ws + szB);
    float* cbuf  = (float*)(ws + szB + szXH);
    short* Winp  = (short*)(ws + szB + szXH + szC);
    short* Woutp = (short*)(ws + szB + szXH + szC + szWin);
    char*  gch   =         ws + szB + szXH + szC + szWin + szWout;
    bool gate_f32 = ws_size >= (szB + szXH + szC + szWin + szWout + 8192ull*512*4);
    short* Wprojp = (short*)gch;   // aliases gbuf; consumed before first conv

    k_pack_w<<<576, 256, 0, stream>>>(ck, Bp);
    k_pack_win<<<24, 256, 0, stream>>>(Win, Winp);
    k_pack_wout<<<16, 256, 0, stream>>>(Wout, Woutp);
    k_pack_wproj<<<24, 256, 0, stream>>>(Wp, Wprojp);
    k_proj_ln_mfma<<<NTOK/64, 256, 0, stream>>>(inputs, Wprojp, gamma, beta, X);
    k_attn_mfma<<<2048, 256, 0, stream>>>(X, Winp, Woutp, inputs, X);  // in-place
    k_pack_x<<<512, 256, 0, stream>>>(X, xh, 0, 1);

    if (gate_f32){
        float* gbuf = (float*)gch;
        for (int s=0; s<16; s++){
            k_conv_mfma<float><<<256, 512, 0, stream>>>(xh, Bp, gbuf);
            k_lstm<float><<<1024, 256, 0, stream>>>(gbuf, cbuf, X, xh, s);
        }
    } else {
        unsigned short* gbuf = (unsigned short*)gch;
        for (int s=0; s<16; s++){
            k_conv_mfma<unsigned short><<<256, 512, 0, stream>>>(xh, Bp, gbuf);
            k_lstm<unsigned short><<<1024, 256, 0, stream>>>(gbuf, cbuf, X, xh, s);
        }
    }
}